// Round 3
// baseline (444.191 us; speedup 1.0000x reference)
//
#include <hip/hip_runtime.h>
#include <stdint.h>

#define NPTS 131072
#define CINC 128
#define COUTC 128
#define WDIM 512
#define K3 27

typedef float f32x4 __attribute__((ext_vector_type(4)));
typedef __bf16 bf16x8 __attribute__((ext_vector_type(8)));

#define GLOAD_LDS16(g, l) \
  __builtin_amdgcn_global_load_lds((const __attribute__((address_space(1))) void*)(g), \
                                   (__attribute__((address_space(3))) void*)(l), 16, 0, 0)

__device__ __forceinline__ unsigned short f2bf(float x){
  union { float f; uint32_t u; } v; v.f = x;
  uint32_t u = v.u;
  uint32_t r = (u + 0x7fffu + ((u >> 16) & 1u)) >> 16;
  return (unsigned short)r;
}

// fused: styles = w @ (aw/sqrt512).T + ab; sn = styles * rsqrt(mean(styles^2))
__global__ void k_styles_all(const float* __restrict__ w, const float* __restrict__ aw,
                             const float* __restrict__ ab, float* __restrict__ sn){
  __shared__ float red[512];
  int t = threadIdx.x;
  int b = t >> 7, c = t & 127;
  const float4* wr = (const float4*)(w + b * WDIM);
  const float4* ar = (const float4*)(aw + c * WDIM);
  float s = 0.f;
  #pragma unroll 4
  for (int i = 0; i < 128; i++){
    float4 wv = wr[i], av = ar[i];
    s += wv.x * av.x + wv.y * av.y + wv.z * av.z + wv.w * av.w;
  }
  s = s * 0.04419417382415922f + ab[c];
  red[t] = s * s;
  __syncthreads();
  for (int off = 256; off > 0; off >>= 1){
    if (t < off) red[t] += red[t + off];
    __syncthreads();
  }
  sn[t] = s * rsqrtf(red[0] * (1.0f / 512.0f));
}

// per cout: wnorm + vmat[cout][cin]=sum_k cw^2 + bpack (B-frag layout, wn-scaled)
__global__ void k_prep_w(const float* __restrict__ cw, float* __restrict__ wnorm,
                         float* __restrict__ vmat, unsigned short* __restrict__ bpack){
  __shared__ float red[128];
  int co = blockIdx.x, cin = threadIdx.x;
  const float* p = cw + co * 3456 + cin * 27;
  float r[27];
  float v = 0.f;
  #pragma unroll
  for (int k = 0; k < 27; k++){ r[k] = p[k]; v += r[k] * r[k]; }
  vmat[co * 128 + cin] = v;
  red[cin] = v;
  __syncthreads();
  for (int off = 64; off > 0; off >>= 1){
    if (cin < off) red[cin] += red[cin + off];
    __syncthreads();
  }
  float wn_s = rsqrtf(red[0] * (1.0f / 3456.0f));
  if (cin == 0) wnorm[co] = wn_s;
  int grp = co >> 4, m = co & 15;
  int kk = cin >> 5, q = (cin >> 3) & 3, j = cin & 7;
  #pragma unroll
  for (int k = 0; k < 27; k++){
    int idx = ((k * 32 + kk * 8 + grp) * 64 + q * 16 + m) * 8 + j;
    bpack[idx] = f2bf(r[k] * wn_s);
  }
}

__global__ void k_dcoefs2(const float* __restrict__ vmat, const float* __restrict__ sn,
                          const float* __restrict__ wnorm, const float* __restrict__ mag,
                          float* __restrict__ dco2){
  int wave = threadIdx.x >> 6, lane = threadIdx.x & 63;
  int pair = blockIdx.x * 8 + wave;
  int b = pair >> 7, co = pair & 127;
  float s0 = sn[b * 128 + lane], s1 = sn[b * 128 + 64 + lane];
  float sum = vmat[co * 128 + lane] * s0 * s0 + vmat[co * 128 + 64 + lane] * s1 * s1;
  for (int off = 32; off > 0; off >>= 1) sum += __shfl_down(sum, off, 64);
  if (lane == 0){
    float wn = wnorm[co];
    dco2[pair] = rsqrtf(sum * wn * wn + 1e-8f) * rsqrtf(mag[0]);
  }
}

__global__ void k_xmod(const float* __restrict__ x, const float* __restrict__ sn,
                       const int* __restrict__ bidx, unsigned short* __restrict__ xpad){
  int gid = blockIdx.x * 256 + threadIdx.x;
  const int total = (NPTS + 1) * 32;
  if (gid >= total) return;
  int n = gid >> 5;
  int c4 = (gid & 31) * 4;
  unsigned short o0, o1, o2, o3;
  if (n < NPTS){
    int b = bidx[n];
    float4 xv = *(const float4*)(x + (size_t)n * CINC + c4);
    float4 sv = *(const float4*)(sn + b * CINC + c4);
    o0 = f2bf(xv.x * sv.x); o1 = f2bf(xv.y * sv.y);
    o2 = f2bf(xv.z * sv.z); o3 = f2bf(xv.w * sv.w);
  } else { o0 = o1 = o2 = o3 = 0; }
  *(ushort4*)(xpad + (size_t)n * CINC + c4) = make_ushort4(o0, o1, o2, o3);
}

__global__ void k_invinit(int* __restrict__ invT){
  int j = blockIdx.x * 256 + threadIdx.x;
  int k = blockIdx.y;
  invT[k * NPTS + j] = NPTS;
}

__global__ void k_invscat(const int* __restrict__ out_idx, const int* __restrict__ in_idx,
                          int* __restrict__ invT){
  int j = blockIdx.x * 256 + threadIdx.x;
  int k = blockIdx.y;
  int o = out_idx[k * NPTS + j];
  if (o < NPTS) invT[k * NPTS + o] = in_idx[k * NPTS + j];
}

// fb8[k][g] = 1 if any of invT[k][g*32..g*32+31] valid
__global__ void k_flags(const int* __restrict__ invT, unsigned char* __restrict__ fb8){
  int k = blockIdx.y;
  int t = threadIdx.x;
  int g = blockIdx.x * 64 + (t >> 2);          // group of 32 rows
  const int* p = invT + (size_t)k * NPTS + g * 32 + (t & 3) * 8;
  int4 a = *(const int4*)p;
  int4 b = *(const int4*)(p + 4);
  int v = (a.x != NPTS) | (a.y != NPTS) | (a.z != NPTS) | (a.w != NPTS)
        | (b.x != NPTS) | (b.y != NPTS) | (b.z != NPTS) | (b.w != NPTS);
  v |= __shfl_xor(v, 1, 64);
  v |= __shfl_xor(v, 2, 64);
  if ((t & 3) == 0) fb8[k * 4096 + g] = (unsigned char)v;
}

// Main conv: block = 256 output rows x 128 couts, 8 waves (4M x 2N), wave tile 64x64.
// LDS 160KB: A double 2x64KB (async gather) + B single 32KB (reg-rotated staging).
// Zero 32-row subtiles (no valid neighbors for this tap) skip staging + MFMA.
__global__ __launch_bounds__(512, 2) void k_conv(
    const unsigned short* __restrict__ xpad,
    const unsigned short* __restrict__ bpack,
    const int* __restrict__ invT,
    const unsigned char* __restrict__ fb8,
    const float* __restrict__ dco2,
    const float* __restrict__ cbias,
    const int* __restrict__ bidx,
    float* __restrict__ out){
  __shared__ __align__(16) unsigned short lds[81920];   // 160 KiB exactly
  unsigned short* Bsh = lds + 2 * 256 * 128;            // last 32KB
  int t = threadIdx.x;
  int wave = t >> 6, lane = t & 63;
  int wm = wave >> 1, wn = wave & 1;
  int q = lane >> 4, m16 = lane & 15;
  int base_pt = blockIdx.x * 256;
  const unsigned char* fbb = fb8 + blockIdx.x * 8;

  f32x4 acc[4][4];   // [mf][jn], rows wm*64+mf*16, cols wn*64+jn*16
  #pragma unroll
  for (int i = 0; i < 4; i++)
    #pragma unroll
    for (int j = 0; j < 4; j++) acc[i][j] = (f32x4){0.f, 0.f, 0.f, 0.f};

  auto prefetchA = [&](int k, int buf, unsigned int flg){
    const int* invk = invT + (size_t)k * NPTS + base_pt;
    unsigned short* Ab = lds + buf * (256 * 128);
    #pragma unroll
    for (int i = 0; i < 8; i++){
      if ((flg >> i) & 1){
        int ch = i * 512 + t;
        int row = ch >> 4;
        int c = (ch & 15) ^ (row & 15);
        int inv = invk[row];
        GLOAD_LDS16(xpad + (size_t)inv * CINC + c * 8, Ab + ch * 8);
      }
    }
  };

  auto flagbyte = [&](int k) -> unsigned int {
    unsigned long long m8 = *(const unsigned long long*)(fbb + (size_t)k * 4096);
    unsigned int f = 0;
    #pragma unroll
    for (int i = 0; i < 8; i++) f |= (((m8 >> (8 * i)) & 1ull) ? 1u : 0u) << i;
    return f;
  };

  // stage B(0) synchronously; prefetch A(0)
  {
    const int4* s = (const int4*)bpack + t * 4;
    int4* d = (int4*)Bsh + t * 4;
    d[0] = s[0]; d[1] = s[1]; d[2] = s[2]; d[3] = s[3];
  }
  unsigned int fl = flagbyte(0);
  prefetchA(0, 0, fl);

  int4 br0, br1, br2, br3;
  for (int k = 0; k < K3; k++){
    unsigned int fln = (k + 1 < K3) ? flagbyte(k + 1) : 0u;
    __syncthreads();                       // A(k) drained, B(k) ds_writes visible
    if (k + 1 < K3){
      prefetchA(k + 1, (k + 1) & 1, fln);  // async, overlaps compute(k)
      const int4* s = (const int4*)(bpack + (size_t)(k + 1) * 16384) + t * 4;
      br0 = s[0]; br1 = s[1]; br2 = s[2]; br3 = s[3];
    }
    unsigned int wfl = (fl >> (wm * 2)) & 3u;
    if (wfl){
      const unsigned short* Ab = lds + (k & 1) * (256 * 128);
      #pragma unroll
      for (int kk = 0; kk < 4; kk++){
        int cA = ((kk * 4 + q) ^ m16) & 15;
        const unsigned short* Ar = Ab + (wm * 64 + m16) * 128 + cA * 8;
        bf16x8 b0 = *(const bf16x8*)(Bsh + ((kk * 8 + wn * 4 + 0) * 64 + lane) * 8);
        bf16x8 b1 = *(const bf16x8*)(Bsh + ((kk * 8 + wn * 4 + 1) * 64 + lane) * 8);
        bf16x8 b2 = *(const bf16x8*)(Bsh + ((kk * 8 + wn * 4 + 2) * 64 + lane) * 8);
        bf16x8 b3 = *(const bf16x8*)(Bsh + ((kk * 8 + wn * 4 + 3) * 64 + lane) * 8);
        if (wfl & 1u){
          bf16x8 a0 = *(const bf16x8*)(Ar + 0 * 128);
          bf16x8 a1 = *(const bf16x8*)(Ar + 16 * 128);
          acc[0][0] = __builtin_amdgcn_mfma_f32_16x16x32_bf16(a0, b0, acc[0][0], 0, 0, 0);
          acc[0][1] = __builtin_amdgcn_mfma_f32_16x16x32_bf16(a0, b1, acc[0][1], 0, 0, 0);
          acc[0][2] = __builtin_amdgcn_mfma_f32_16x16x32_bf16(a0, b2, acc[0][2], 0, 0, 0);
          acc[0][3] = __builtin_amdgcn_mfma_f32_16x16x32_bf16(a0, b3, acc[0][3], 0, 0, 0);
          acc[1][0] = __builtin_amdgcn_mfma_f32_16x16x32_bf16(a1, b0, acc[1][0], 0, 0, 0);
          acc[1][1] = __builtin_amdgcn_mfma_f32_16x16x32_bf16(a1, b1, acc[1][1], 0, 0, 0);
          acc[1][2] = __builtin_amdgcn_mfma_f32_16x16x32_bf16(a1, b2, acc[1][2], 0, 0, 0);
          acc[1][3] = __builtin_amdgcn_mfma_f32_16x16x32_bf16(a1, b3, acc[1][3], 0, 0, 0);
        }
        if (wfl & 2u){
          bf16x8 a2 = *(const bf16x8*)(Ar + 32 * 128);
          bf16x8 a3 = *(const bf16x8*)(Ar + 48 * 128);
          acc[2][0] = __builtin_amdgcn_mfma_f32_16x16x32_bf16(a2, b0, acc[2][0], 0, 0, 0);
          acc[2][1] = __builtin_amdgcn_mfma_f32_16x16x32_bf16(a2, b1, acc[2][1], 0, 0, 0);
          acc[2][2] = __builtin_amdgcn_mfma_f32_16x16x32_bf16(a2, b2, acc[2][2], 0, 0, 0);
          acc[2][3] = __builtin_amdgcn_mfma_f32_16x16x32_bf16(a2, b3, acc[2][3], 0, 0, 0);
          acc[3][0] = __builtin_amdgcn_mfma_f32_16x16x32_bf16(a3, b0, acc[3][0], 0, 0, 0);
          acc[3][1] = __builtin_amdgcn_mfma_f32_16x16x32_bf16(a3, b1, acc[3][1], 0, 0, 0);
          acc[3][2] = __builtin_amdgcn_mfma_f32_16x16x32_bf16(a3, b2, acc[3][2], 0, 0, 0);
          acc[3][3] = __builtin_amdgcn_mfma_f32_16x16x32_bf16(a3, b3, acc[3][3], 0, 0, 0);
        }
      }
    }
    __syncthreads();                       // all done reading Bsh (A(k+1) drains here too)
    if (k + 1 < K3){
      int4* d = (int4*)Bsh + t * 4;
      d[0] = br0; d[1] = br1; d[2] = br2; d[3] = br3;
    }
    fl = fln;
  }

  // epilogue: demod + bias + leaky*sqrt2 + clip
  const float S2 = 1.41421356237309515f;
  #pragma unroll
  for (int mf = 0; mf < 4; mf++){
    #pragma unroll
    for (int r = 0; r < 4; r++){
      int n = base_pt + wm * 64 + mf * 16 + q * 4 + r;   // D: row=(lane>>4)*4+reg
      int b = bidx[n];
      const float* dc = dco2 + b * COUTC;
      float* orow = out + (size_t)n * COUTC;
      #pragma unroll
      for (int jn = 0; jn < 4; jn++){
        int col = wn * 64 + jn * 16 + m16;               // D: col=lane&15
        float v = acc[mf][jn][r] * dc[col] + cbias[col];
        v = (v < 0.f ? 0.2f * v : v) * S2;
        v = fminf(fmaxf(v, -256.f), 256.f);
        orow[col] = v;
      }
    }
  }
}

extern "C" void kernel_launch(void* const* d_in, const int* in_sizes, int n_in,
                              void* d_out, int out_size, void* d_ws, size_t ws_size,
                              hipStream_t stream){
  const float* x   = (const float*)d_in[0];
  const float* w   = (const float*)d_in[1];
  const float* aw  = (const float*)d_in[2];
  const float* ab  = (const float*)d_in[3];
  const float* cw  = (const float*)d_in[4];
  const float* cb  = (const float*)d_in[5];
  const float* mag = (const float*)d_in[6];
  const int* bidx    = (const int*)d_in[7];
  const int* in_idx  = (const int*)d_in[8];
  const int* out_idx = (const int*)d_in[9];
  float* out = (float*)d_out;
  char* ws = (char*)d_ws;

  float* sn     = (float*)(ws + 0);         // 2048 B
  float* wnorm  = (float*)(ws + 2048);      // 512 B
  float* dco2   = (float*)(ws + 2560);      // 2048 B
  float* vmat   = (float*)(ws + 8192);      // 65536 B  (dead after k_dcoefs2)
  unsigned char* fb8 = (unsigned char*)(ws + 8192 + 65536 + 4096); // placed after vmat? no:
  // fb8 needs 110592 B; place it after invT (see below).
  unsigned short* bpack = (unsigned short*)(ws + 73728);    // 884736 B
  unsigned short* xpad  = (unsigned short*)(ws + 958464);   // 33554688 B
  int* invT     = (int*)(ws + 34513152);                    // 14155776 B -> 48668928
  fb8 = (unsigned char*)(ws + 48668928);                    // 110592 B -> 48779520

  k_prep_w<<<128, 128, 0, stream>>>(cw, wnorm, vmat, bpack);
  k_styles_all<<<1, 512, 0, stream>>>(w, aw, ab, sn);
  k_dcoefs2<<<64, 512, 0, stream>>>(vmat, sn, wnorm, mag, dco2);
  k_xmod<<<16385, 256, 0, stream>>>(x, sn, bidx, xpad);
  dim3 gi(512, 27);
  k_invinit<<<gi, 256, 0, stream>>>(invT);
  k_invscat<<<gi, 256, 0, stream>>>(out_idx, in_idx, invT);
  dim3 gf(64, 27);
  k_flags<<<gf, 256, 0, stream>>>(invT, fb8);
  k_conv<<<512, 512, 0, stream>>>(xpad, bpack, invT, fb8, dco2, cb, bidx, out);
}